// Round 1
// baseline (2030.411 us; speedup 1.0000x reference)
//
#include <hip/hip_runtime.h>
#include <math.h>
#include <stdint.h>

#define BLOCK 256

__global__ void zero_kernel(float* out) {
    if (threadIdx.x == 0 && blockIdx.x == 0) out[0] = 0.0f;
}

__global__ __launch_bounds__(BLOCK) void ce_loss_kernel(
    const float* __restrict__ logits,
    const int*   __restrict__ target,
    const float* __restrict__ cw,
    float*       __restrict__ out,
    int C)
{
    const int row = blockIdx.x;
    const float* rp = logits + (size_t)row * (size_t)C;
    const int tid = threadIdx.x;

    // online logsumexp state
    float m = -INFINITY;
    float s = 0.0f;

    // ---- alignment prologue: rows are only 4B-aligned (C odd) ----
    int pro = (int)(((16u - ((uintptr_t)rp & 15u)) & 15u) >> 2);
    if (pro > C) pro = C;
    for (int i = tid; i < pro; i += BLOCK) {
        float x = rp[i];
        if (x > m) { s *= __expf(m - x); m = x; }
        s += __expf(x - m);
    }

    // ---- float4 main loop ----
    const float4* rp4 = (const float4*)(rp + pro);
    const int n4 = (C - pro) >> 2;
    for (int i = tid; i < n4; i += BLOCK) {
        float4 v = rp4[i];
        float xm = fmaxf(fmaxf(v.x, v.y), fmaxf(v.z, v.w));
        if (xm > m) { s *= __expf(m - xm); m = xm; }  // rare rescale
        s += __expf(v.x - m) + __expf(v.y - m)
           + __expf(v.z - m) + __expf(v.w - m);
    }

    // ---- epilogue remainder ----
    for (int i = pro + (n4 << 2) + tid; i < C; i += BLOCK) {
        float x = rp[i];
        if (x > m) { s *= __expf(m - x); m = x; }
        s += __expf(x - m);
    }

    // ---- wave (64-lane) butterfly reduction of (m, s) ----
    for (int off = 32; off > 0; off >>= 1) {
        float om = __shfl_xor(m, off, 64);
        float os = __shfl_xor(s, off, 64);
        float nm = fmaxf(m, om);
        s = s * __expf(m - nm) + os * __expf(om - nm);
        m = nm;
    }

    // ---- cross-wave combine in LDS (4 waves) ----
    __shared__ float sm[BLOCK / 64];
    __shared__ float ss[BLOCK / 64];
    const int wave = tid >> 6;
    const int lane = tid & 63;
    if (lane == 0) { sm[wave] = m; ss[wave] = s; }
    __syncthreads();

    if (tid == 0) {
        float M = sm[0], S = ss[0];
        #pragma unroll
        for (int w2 = 1; w2 < BLOCK / 64; ++w2) {
            float om = sm[w2], os = ss[w2];
            float nm = fmaxf(M, om);
            S = S * __expf(M - nm) + os * __expf(om - nm);
            M = nm;
        }
        const int t  = target[row];
        const float xt = rp[t];
        const float wt = cw[t];
        const float loss = wt * (M + logf(S) - xt);
        atomicAdd(out, loss);
    }
}

extern "C" void kernel_launch(void* const* d_in, const int* in_sizes, int n_in,
                              void* d_out, int out_size, void* d_ws, size_t ws_size,
                              hipStream_t stream) {
    const float* logits = (const float*)d_in[0];
    const int*   target = (const int*)d_in[1];
    const float* cw     = (const float*)d_in[2];
    float* out = (float*)d_out;

    const int N = in_sizes[1];                 // 8192 rows
    const int C = in_sizes[0] / in_sizes[1];   // 50257 classes

    zero_kernel<<<1, 1, 0, stream>>>(out);
    ce_loss_kernel<<<N, BLOCK, 0, stream>>>(logits, target, cw, out, C);
}